// Round 10
// baseline (3657.975 us; speedup 1.0000x reference)
//
#include <hip/hip_runtime.h>

#define NN 100000
#define CC 64
#define KKK 343

typedef __bf16 bf16x8 __attribute__((ext_vector_type(8)));
typedef float  f32x4  __attribute__((ext_vector_type(4)));

// round-to-nearest-even fp32 -> bf16 (finite inputs)
__device__ __forceinline__ unsigned short f2bf(float f) {
    unsigned int u = __float_as_uint(f);
    unsigned int r = u + 0x7fffu + ((u >> 16) & 1u);
    return (unsigned short)(r >> 16);
}

// ---------------------------------------------------------------------------
// P1: feats fp32 -> bf16 hi/lo, with zero pad row at index NN
// ---------------------------------------------------------------------------
__global__ __launch_bounds__(256) void k_prep_feats(
    const float* __restrict__ feats, unsigned short* __restrict__ fh,
    unsigned short* __restrict__ fl)
{
    const int total4 = (NN + 1) * CC / 4;
    int i = blockIdx.x * 256 + threadIdx.x;
    if (i >= total4) return;
    float4 v = make_float4(0.f, 0.f, 0.f, 0.f);
    if (i < NN * CC / 4) v = ((const float4*)feats)[i];
    ushort4 h, l;
    float hf;
    h.x = f2bf(v.x); hf = __uint_as_float((unsigned)h.x << 16); l.x = f2bf(v.x - hf);
    h.y = f2bf(v.y); hf = __uint_as_float((unsigned)h.y << 16); l.y = f2bf(v.y - hf);
    h.z = f2bf(v.z); hf = __uint_as_float((unsigned)h.z << 16); l.z = f2bf(v.z - hf);
    h.w = f2bf(v.w); hf = __uint_as_float((unsigned)h.w << 16); l.w = f2bf(v.w - hf);
    ((ushort4*)fh)[i] = h;
    ((ushort4*)fl)[i] = l;
}

// ---------------------------------------------------------------------------
// P2: w_dw [k][ci][co] fp32 -> transposed bf16 hi/lo [k][co][ci]
// ---------------------------------------------------------------------------
__global__ __launch_bounds__(256) void k_prep_w(
    const float* __restrict__ w_dw, unsigned short* __restrict__ wth,
    unsigned short* __restrict__ wtl)
{
    const int k = blockIdx.x;
    const float* W = w_dw + (long)k * 4096;
    unsigned short* th = wth + (long)k * 4096;
    unsigned short* tl = wtl + (long)k * 4096;
    for (int e = threadIdx.x; e < 4096; e += 256) {
        int ci = e >> 6, co = e & 63;
        float v = W[e];
        unsigned short hs = f2bf(v);
        float hf = __uint_as_float((unsigned)hs << 16);
        unsigned short ls = f2bf(v - hf);
        th[co * 64 + ci] = hs;
        tl[co * 64 + ci] = ls;
    }
}

// ---------------------------------------------------------------------------
// K1: sparse conv via MFMA, split-bf16 (3 mfma per tile-product).
// ZERO LDS / ZERO BARRIERS: R3/R5 were LDS-BW-bound (144 KB/blk/iter ->
// ~756us). A-gather loads land DIRECTLY in fragment layout (lane fr=l&15,
// fc=l>>4 reads fh[ridx(fr)*64 + ks*32 + fc*8]); wave's 32 rows are private.
// B fragments load per-lane from global (16 KB/iter shared by all waves ->
// L1-served). Row indices distributed by 2 shfls. Waves fully independent.
// ---------------------------------------------------------------------------
__global__ __launch_bounds__(256, 4) void k_conv_mfma(
    const unsigned short* __restrict__ fh, const unsigned short* __restrict__ fl,
    const unsigned short* __restrict__ wth, const unsigned short* __restrict__ wtl,
    const float* __restrict__ b_dw, const int* __restrict__ nbr,
    float* __restrict__ xout)
{
    const int t  = threadIdx.x;
    const int wv = t >> 6;
    const int l  = t & 63;
    const int v0 = blockIdx.x * 128 + wv * 32;   // wave's base voxel row
    const int myrow = v0 + (l & 31);
    const bool rowok = myrow < NN;
    const long nbase = (long)myrow * KKK;
    const int fr = l & 15;          // fragment row / out-channel-in-tile
    const int coff = (l >> 4) * 8;  // fragment K-chunk element offset

    f32x4 acc[2][4];
#pragma unroll
    for (int i = 0; i < 2; ++i)
#pragma unroll
        for (int j = 0; j < 4; ++j) acc[i][j] = (f32x4){0.f, 0.f, 0.f, 0.f};

#define MM3(RT, CT, AH, AL, BH, BL)                                          \
    acc[RT][CT] = __builtin_amdgcn_mfma_f32_16x16x32_bf16(                   \
        AH, BH, acc[RT][CT], 0, 0, 0);                                       \
    acc[RT][CT] = __builtin_amdgcn_mfma_f32_16x16x32_bf16(                   \
        AH, BL, acc[RT][CT], 0, 0, 0);                                       \
    acc[RT][CT] = __builtin_amdgcn_mfma_f32_16x16x32_bf16(                   \
        AL, BH, acc[RT][CT], 0, 0, 0);

    int idx = rowok ? nbr[nbase] : NN;

#pragma unroll 1
    for (int k = 0; k < KKK; ++k) {
        // distribute this iter's gather rows to fragment lanes
        const int r0 = __shfl(idx, fr);
        const int r1 = __shfl(idx, fr + 16);
        // prefetch next iter's index (independent of below)
        const int idxn = (k + 1 < KKK) ? (rowok ? nbr[nbase + k + 1] : NN) : NN;

        // ---- A fragments, direct from global (both ksteps, hi+lo) ----
        const unsigned short* a0 = fh + (long)r0 * 64 + coff;
        const unsigned short* a1 = fh + (long)r1 * 64 + coff;
        const unsigned short* a0l = fl + (long)r0 * 64 + coff;
        const unsigned short* a1l = fl + (long)r1 * 64 + coff;
        bf16x8 ah0k0 = *(const bf16x8*)(a0);
        bf16x8 ah0k1 = *(const bf16x8*)(a0 + 32);
        bf16x8 ah1k0 = *(const bf16x8*)(a1);
        bf16x8 ah1k1 = *(const bf16x8*)(a1 + 32);
        bf16x8 al0k0 = *(const bf16x8*)(a0l);
        bf16x8 al0k1 = *(const bf16x8*)(a0l + 32);
        bf16x8 al1k0 = *(const bf16x8*)(a1l);
        bf16x8 al1k1 = *(const bf16x8*)(a1l + 32);

        const unsigned short* wb  = wth + (long)k * 4096 + fr * 64 + coff;
        const unsigned short* wbl = wtl + (long)k * 4096 + fr * 64 + coff;

        // ---- kstep 0 ----
        {
            bf16x8 bh0 = *(const bf16x8*)(wb);
            bf16x8 bh1 = *(const bf16x8*)(wb + 1024);
            bf16x8 bh2 = *(const bf16x8*)(wb + 2048);
            bf16x8 bh3 = *(const bf16x8*)(wb + 3072);
            bf16x8 bl0 = *(const bf16x8*)(wbl);
            bf16x8 bl1 = *(const bf16x8*)(wbl + 1024);
            bf16x8 bl2 = *(const bf16x8*)(wbl + 2048);
            bf16x8 bl3 = *(const bf16x8*)(wbl + 3072);
            MM3(0, 0, ah0k0, al0k0, bh0, bl0)
            MM3(0, 1, ah0k0, al0k0, bh1, bl1)
            MM3(0, 2, ah0k0, al0k0, bh2, bl2)
            MM3(0, 3, ah0k0, al0k0, bh3, bl3)
            MM3(1, 0, ah1k0, al1k0, bh0, bl0)
            MM3(1, 1, ah1k0, al1k0, bh1, bl1)
            MM3(1, 2, ah1k0, al1k0, bh2, bl2)
            MM3(1, 3, ah1k0, al1k0, bh3, bl3)
        }
        // ---- kstep 1 (K elements 32..63) ----
        {
            bf16x8 bh0 = *(const bf16x8*)(wb + 32);
            bf16x8 bh1 = *(const bf16x8*)(wb + 1024 + 32);
            bf16x8 bh2 = *(const bf16x8*)(wb + 2048 + 32);
            bf16x8 bh3 = *(const bf16x8*)(wb + 3072 + 32);
            bf16x8 bl0 = *(const bf16x8*)(wbl + 32);
            bf16x8 bl1 = *(const bf16x8*)(wbl + 1024 + 32);
            bf16x8 bl2 = *(const bf16x8*)(wbl + 2048 + 32);
            bf16x8 bl3 = *(const bf16x8*)(wbl + 3072 + 32);
            MM3(0, 0, ah0k1, al0k1, bh0, bl0)
            MM3(0, 1, ah0k1, al0k1, bh1, bl1)
            MM3(0, 2, ah0k1, al0k1, bh2, bl2)
            MM3(0, 3, ah0k1, al0k1, bh3, bl3)
            MM3(1, 0, ah1k1, al1k1, bh0, bl0)
            MM3(1, 1, ah1k1, al1k1, bh1, bl1)
            MM3(1, 2, ah1k1, al1k1, bh2, bl2)
            MM3(1, 3, ah1k1, al1k1, bh3, bl3)
        }
        idx = idxn;
    }
#undef MM3

    // ---- epilogue: C/D layout col=l&15, row=(l>>4)*4+j ----
#pragma unroll
    for (int ct = 0; ct < 4; ++ct) {
        float bias = b_dw[ct * 16 + fr];
#pragma unroll
        for (int rt = 0; rt < 2; ++rt)
#pragma unroll
            for (int j = 0; j < 4; ++j) {
                int row = v0 + rt * 16 + (l >> 4) * 4 + j;
                if (row < NN)
                    xout[(long)row * 64 + ct * 16 + fr] = acc[rt][ct][j] + bias;
            }
    }
}

// ---------------------------------------------------------------------------
// K2: GroupNorm(1,C) stats per batch: sum, sumsq, count
// stats layout: [s0, s1, q0, q1, cnt0, cnt1]
// ---------------------------------------------------------------------------
__global__ __launch_bounds__(256) void k_gnstats(
    const float* __restrict__ x, const int* __restrict__ batch_ids,
    float* __restrict__ stats)
{
    __shared__ float red[4][8];
    float s0 = 0.f, s1 = 0.f, q0 = 0.f, q1 = 0.f, c0 = 0.f, c1 = 0.f;
    const int total4 = NN * CC / 4;
    for (int i = blockIdx.x * blockDim.x + threadIdx.x; i < total4;
         i += gridDim.x * blockDim.x) {
        float4 v = ((const float4*)x)[i];
        int b = batch_ids[i >> 4];
        float ss = (v.x + v.y) + (v.z + v.w);
        float qq = fmaf(v.x, v.x, fmaf(v.y, v.y, fmaf(v.z, v.z, v.w * v.w)));
        bool b0 = (b == 0);
        s0 += b0 ? ss : 0.f;  s1 += b0 ? 0.f : ss;
        q0 += b0 ? qq : 0.f;  q1 += b0 ? 0.f : qq;
        c0 += b0 ? 4.f : 0.f; c1 += b0 ? 0.f : 4.f;
    }
#pragma unroll
    for (int off = 32; off > 0; off >>= 1) {
        s0 += __shfl_down(s0, off); s1 += __shfl_down(s1, off);
        q0 += __shfl_down(q0, off); q1 += __shfl_down(q1, off);
        c0 += __shfl_down(c0, off); c1 += __shfl_down(c1, off);
    }
    const int lane = threadIdx.x & 63, w = threadIdx.x >> 6;
    if (lane == 0) {
        red[w][0] = s0; red[w][1] = s1; red[w][2] = q0;
        red[w][3] = q1; red[w][4] = c0; red[w][5] = c1;
    }
    __syncthreads();
    if (threadIdx.x < 6) {
        float tot = red[0][threadIdx.x] + red[1][threadIdx.x] +
                    red[2][threadIdx.x] + red[3][threadIdx.x];
        atomicAdd(&stats[threadIdx.x], tot);
    }
}

// ---------------------------------------------------------------------------
// shared helpers for K3/K5
// ---------------------------------------------------------------------------
__device__ __forceinline__ void stage_xn(
    float* __restrict__ sxn, const float* __restrict__ x,
    const int* __restrict__ batch_ids, const float* __restrict__ gn_gamma,
    const float* __restrict__ gn_beta, const float* __restrict__ stats,
    int v0, int t)
{
    float mean[2], rstd[2];
#pragma unroll
    for (int b = 0; b < 2; ++b) {
        float cn  = stats[4 + b];
        float m   = stats[b] / cn;
        float var = stats[2 + b] / cn - m * m;
        mean[b] = m;
        rstd[b] = rsqrtf(var + 1e-6f);
    }
#pragma unroll
    for (int u = 0; u < 4; ++u) {
        int fi = t + u * 256;
        int row = fi >> 4, c4 = fi & 15;
        int vv = v0 + row;
        float4 val = make_float4(0.f, 0.f, 0.f, 0.f);
        if (vv < NN) {
            float4 xv = *(const float4*)(x + ((long)vv << 6) + (c4 << 2));
            float4 g  = *(const float4*)(gn_gamma + (c4 << 2));
            float4 be = *(const float4*)(gn_beta + (c4 << 2));
            int b = batch_ids[vv];
            float m = mean[b], rs = rstd[b];
            val.x = (xv.x - m) * rs * g.x + be.x;
            val.y = (xv.y - m) * rs * g.y + be.y;
            val.z = (xv.z - m) * rs * g.z + be.z;
            val.w = (xv.w - m) * rs * g.w + be.w;
        }
        *(float4*)&sxn[row * 68 + (c4 << 2)] = val;
    }
}

__device__ __forceinline__ void gemm_h(
    const float* __restrict__ sxn, const float* __restrict__ w_pw1,
    int r, int c, float h[4][16])
{
#pragma unroll 2
    for (int ci = 0; ci < 64; ++ci) {
        float a[4];
#pragma unroll
        for (int i = 0; i < 4; ++i) a[i] = sxn[((r << 2) + i) * 68 + ci];
        const float4* wr = (const float4*)(w_pw1 + ci * 256 + (c << 4));
        float4 w4[4] = {wr[0], wr[1], wr[2], wr[3]};
#pragma unroll
        for (int i = 0; i < 4; ++i)
#pragma unroll
            for (int q = 0; q < 4; ++q) {
                h[i][q * 4 + 0] = fmaf(a[i], w4[q].x, h[i][q * 4 + 0]);
                h[i][q * 4 + 1] = fmaf(a[i], w4[q].y, h[i][q * 4 + 1]);
                h[i][q * 4 + 2] = fmaf(a[i], w4[q].z, h[i][q * 4 + 2]);
                h[i][q * 4 + 3] = fmaf(a[i], w4[q].w, h[i][q * 4 + 3]);
            }
    }
}

// ---------------------------------------------------------------------------
// K3: h = relu(GN(x) @ w_pw1); gx2[b][c'] += sum_v h^2
// ---------------------------------------------------------------------------
__global__ __launch_bounds__(256) void k_pw1_grn(
    const float* __restrict__ x, const int* __restrict__ batch_ids,
    const float* __restrict__ gn_gamma, const float* __restrict__ gn_beta,
    const float* __restrict__ w_pw1, const float* __restrict__ stats,
    float* __restrict__ gx2)
{
    __shared__ float sxn[64 * 68];
    __shared__ float red[16 * 257];
    const int t = threadIdx.x;
    const int v0 = blockIdx.x * 64;
    stage_xn(sxn, x, batch_ids, gn_gamma, gn_beta, stats, v0, t);
    __syncthreads();
    const int r = t >> 4, c = t & 15;
    float h[4][16] = {};
    gemm_h(sxn, w_pw1, r, c, h);
#pragma unroll
    for (int i = 0; i < 4; ++i)
#pragma unroll
        for (int jj = 0; jj < 16; ++jj) h[i][jj] = fmaxf(h[i][jj], 0.f);

    int bv[4];
#pragma unroll
    for (int i = 0; i < 4; ++i) {
        int vv = v0 + (r << 2) + i;
        bv[i] = (vv < NN) ? batch_ids[vv] : -1;
    }
#pragma unroll
    for (int b = 0; b < 2; ++b) {
        float p[16] = {};
#pragma unroll
        for (int i = 0; i < 4; ++i)
            if (bv[i] == b)
#pragma unroll
                for (int jj = 0; jj < 16; ++jj)
                    p[jj] = fmaf(h[i][jj], h[i][jj], p[jj]);
#pragma unroll
        for (int jj = 0; jj < 16; ++jj)
            red[r * 257 + (c << 4) + jj] = p[jj];
        __syncthreads();
        float sum = 0.f;
#pragma unroll
        for (int rr = 0; rr < 16; ++rr) sum += red[rr * 257 + t];
        if (sum != 0.f) atomicAdd(&gx2[b * 256 + t], sum);
        __syncthreads();
    }
}

// ---------------------------------------------------------------------------
// K4: nx[b][c'] = gx / (mean_c'(gx) + eps), gx = sqrt(gx2). One block.
// ---------------------------------------------------------------------------
__global__ __launch_bounds__(256) void k_grn_nx(
    const float* __restrict__ gx2, float* __restrict__ nx)
{
    __shared__ float red[8];
    const int t = threadIdx.x;
#pragma unroll
    for (int b = 0; b < 2; ++b) {
        float g = sqrtf(gx2[b * 256 + t]);
        float s = g;
#pragma unroll
        for (int off = 32; off > 0; off >>= 1) s += __shfl_down(s, off);
        if ((t & 63) == 0) red[t >> 6] = s;
        __syncthreads();
        float meang = (red[0] + red[1] + red[2] + red[3]) * (1.f / 256.f);
        nx[b * 256 + t] = g / (meang + 1e-6f);
        __syncthreads();
    }
}

// ---------------------------------------------------------------------------
// K5: recompute xn and h, apply GRN, y @ w_pw2, + identity -> out
// ---------------------------------------------------------------------------
__global__ __launch_bounds__(256) void k_pw2_out(
    const float* __restrict__ x, const float* __restrict__ feats,
    const int* __restrict__ batch_ids, const float* __restrict__ gn_gamma,
    const float* __restrict__ gn_beta, const float* __restrict__ w_pw1,
    const float* __restrict__ grn_gamma, const float* __restrict__ grn_beta,
    const float* __restrict__ w_pw2, const float* __restrict__ stats,
    const float* __restrict__ nx, float* __restrict__ out)
{
    __shared__ float smem[64 * 132];
    const int t = threadIdx.x;
    const int v0 = blockIdx.x * 64;
    stage_xn(smem, x, batch_ids, gn_gamma, gn_beta, stats, v0, t);
    __syncthreads();
    const int r = t >> 4, c = t & 15;
    float h[4][16] = {};
    gemm_h(smem, w_pw1, r, c, h);

    int bv[4];
#pragma unroll
    for (int i = 0; i < 4; ++i) {
        int vv = v0 + (r << 2) + i;
        bv[i] = (vv < NN) ? batch_ids[vv] : 0;
    }
#pragma unroll
    for (int q = 0; q < 4; ++q) {
        const int ch = (c << 4) + (q << 2);
        float4 ga  = *(const float4*)(grn_gamma + ch);
        float4 gbv = *(const float4*)(grn_beta + ch);
        float4 n0  = *(const float4*)(nx + ch);
        float4 n1  = *(const float4*)(nx + 256 + ch);
#pragma unroll
        for (int i = 0; i < 4; ++i) {
            float4 ns = bv[i] ? n1 : n0;
            float h0 = fmaxf(h[i][q * 4 + 0], 0.f);
            float h1 = fmaxf(h[i][q * 4 + 1], 0.f);
            float h2 = fmaxf(h[i][q * 4 + 2], 0.f);
            float h3 = fmaxf(h[i][q * 4 + 3], 0.f);
            h[i][q * 4 + 0] = fmaf(ga.x, h0 * ns.x, gbv.x) + h0;
            h[i][q * 4 + 1] = fmaf(ga.y, h1 * ns.y, gbv.y) + h1;
            h[i][q * 4 + 2] = fmaf(ga.z, h2 * ns.z, gbv.z) + h2;
            h[i][q * 4 + 3] = fmaf(ga.w, h3 * ns.w, gbv.w) + h3;
        }
    }

    float acc2[4][4] = {};
#pragma unroll
    for (int half = 0; half < 2; ++half) {
        __syncthreads();
        if ((c >> 3) == half) {
            const int ch0 = (c & 7) << 4;
#pragma unroll
            for (int i = 0; i < 4; ++i) {
                float4* dst = (float4*)&smem[((r << 2) + i) * 132 + ch0];
                dst[0] = make_float4(h[i][0],  h[i][1],  h[i][2],  h[i][3]);
                dst[1] = make_float4(h[i][4],  h[i][5],  h[i][6],  h[i][7]);
                dst[2] = make_float4(h[i][8],  h[i][9],  h[i][10], h[i][11]);
                dst[3] = make_float4(h[i][12], h[i][13], h[i][14], h[i][15]);
            }
        }
        __syncthreads();
#pragma unroll 4
        for (int kk = 0; kk < 128; ++kk) {
            float a0 = smem[((r << 2) + 0) * 132 + kk];
            float a1 = smem[((r << 2) + 1) * 132 + kk];
            float a2 = smem[((r << 2) + 2) * 132 + kk];
            float a3 = smem[((r << 2) + 3) * 132 + kk];
            float4 w = *(const float4*)(w_pw2 + (half * 128 + kk) * 64 + (c << 2));
            acc2[0][0] = fmaf(a0, w.x, acc2[0][0]); acc2[0][1] = fmaf(a0, w.y, acc2[0][1]);
            acc2[0][2] = fmaf(a0, w.z, acc2[0][2]); acc2[0][3] = fmaf(a0, w.w, acc2[0][3]);
            acc2[1][0] = fmaf(a1, w.x, acc2[1][0]); acc2[1][1] = fmaf(a1, w.y, acc2[1][1]);
            acc2[1][2] = fmaf(a1, w.z, acc2[1][2]); acc2[1][3] = fmaf(a1, w.w, acc2[1][3]);
            acc2[2][0] = fmaf(a2, w.x, acc2[2][0]); acc2[2][1] = fmaf(a2, w.y, acc2[2][1]);
            acc2[2][2] = fmaf(a2, w.z, acc2[2][2]); acc2[2][3] = fmaf(a2, w.w, acc2[2][3]);
            acc2[3][0] = fmaf(a3, w.x, acc2[3][0]); acc2[3][1] = fmaf(a3, w.y, acc2[3][1]);
            acc2[3][2] = fmaf(a3, w.z, acc2[3][2]); acc2[3][3] = fmaf(a3, w.w, acc2[3][3]);
        }
    }
#pragma unroll
    for (int i = 0; i < 4; ++i) {
        int vv = v0 + (r << 2) + i;
        if (vv < NN) {
            float4 fin = *(const float4*)(feats + ((long)vv << 6) + (c << 2));
            float4 o = make_float4(fin.x + acc2[i][0], fin.y + acc2[i][1],
                                   fin.z + acc2[i][2], fin.w + acc2[i][3]);
            *(float4*)(out + ((long)vv << 6) + (c << 2)) = o;
        }
    }
}

// ---------------------------------------------------------------------------
extern "C" void kernel_launch(void* const* d_in, const int* in_sizes, int n_in,
                              void* d_out, int out_size, void* d_ws, size_t ws_size,
                              hipStream_t stream)
{
    const float* feats     = (const float*)d_in[0];
    const float* w_dw      = (const float*)d_in[1];
    const float* b_dw      = (const float*)d_in[2];
    const float* gn_gamma  = (const float*)d_in[3];
    const float* gn_beta   = (const float*)d_in[4];
    const float* w_pw1     = (const float*)d_in[5];
    const float* grn_gamma = (const float*)d_in[6];
    const float* grn_beta  = (const float*)d_in[7];
    const float* w_pw2     = (const float*)d_in[8];
    const int*   nbr       = (const int*)d_in[9];
    const int*   batch_ids = (const int*)d_in[10];
    float* out = (float*)d_out;

    char* ws = (char*)d_ws;
    float*          x     = (float*)ws;                    ws += (size_t)NN * CC * 4;
    unsigned short* fh    = (unsigned short*)ws;           ws += (size_t)(NN + 1) * CC * 2;
    unsigned short* fl    = (unsigned short*)ws;           ws += (size_t)(NN + 1) * CC * 2;
    unsigned short* wth   = (unsigned short*)ws;           ws += (size_t)KKK * 4096 * 2;
    unsigned short* wtl   = (unsigned short*)ws;           ws += (size_t)KKK * 4096 * 2;
    float*          stats = (float*)ws;                    ws += 8 * 4;
    float*          gx2   = (float*)ws;                    ws += 512 * 4;
    float*          nx    = (float*)ws;

    hipMemsetAsync(stats, 0, (8 + 512 + 512) * sizeof(float), stream);

    const int pf_blocks = ((NN + 1) * CC / 4 + 255) / 256;
    k_prep_feats<<<pf_blocks, 256, 0, stream>>>(feats, fh, fl);
    k_prep_w<<<KKK, 256, 0, stream>>>(w_dw, wth, wtl);

    const int cblk = (NN + 127) / 128;          // 782
    k_conv_mfma<<<cblk, 256, 0, stream>>>(fh, fl, wth, wtl, b_dw, nbr, x);

    const int nblk = (NN + 63) / 64;            // 1563
    k_gnstats<<<1024, 256, 0, stream>>>(x, batch_ids, stats);
    k_pw1_grn<<<nblk, 256, 0, stream>>>(x, batch_ids, gn_gamma, gn_beta,
                                        w_pw1, stats, gx2);
    k_grn_nx<<<1, 256, 0, stream>>>(gx2, nx);
    k_pw2_out<<<nblk, 256, 0, stream>>>(x, feats, batch_ids, gn_gamma, gn_beta,
                                        w_pw1, grn_gamma, grn_beta, w_pw2,
                                        stats, nx, out);
}

// Round 11
// 1282.348 us; speedup vs baseline: 2.8526x; 2.8526x over previous
//
#include <hip/hip_runtime.h>

#define NN 100000
#define CC 64
#define KKK 343

typedef __bf16 bf16x8 __attribute__((ext_vector_type(8)));
typedef float  f32x4  __attribute__((ext_vector_type(4)));

// round-to-nearest-even fp32 -> bf16 (finite inputs)
__device__ __forceinline__ unsigned short f2bf(float f) {
    unsigned int u = __float_as_uint(f);
    unsigned int r = u + 0x7fffu + ((u >> 16) & 1u);
    return (unsigned short)(r >> 16);
}

__device__ __forceinline__ void gll16(const unsigned short* g, unsigned short* l) {
    __builtin_amdgcn_global_load_lds(
        (const __attribute__((address_space(1))) unsigned int*)g,
        (__attribute__((address_space(3))) unsigned int*)l, 16, 0, 0);
}

// ---------------------------------------------------------------------------
// P1: feats fp32 -> bf16 (single array), zero pad row at index NN
// ---------------------------------------------------------------------------
__global__ __launch_bounds__(256) void k_prep_feats(
    const float* __restrict__ feats, unsigned short* __restrict__ fh)
{
    const int total4 = (NN + 1) * CC / 4;
    int i = blockIdx.x * 256 + threadIdx.x;
    if (i >= total4) return;
    float4 v = make_float4(0.f, 0.f, 0.f, 0.f);
    if (i < NN * CC / 4) v = ((const float4*)feats)[i];
    ushort4 h;
    h.x = f2bf(v.x); h.y = f2bf(v.y); h.z = f2bf(v.z); h.w = f2bf(v.w);
    ((ushort4*)fh)[i] = h;
}

// ---------------------------------------------------------------------------
// P2: w_dw [k][ci][co] fp32 -> transposed bf16 hi/lo [k][co][ci]
// (W keeps hi+lo split: reconstructs w to ~2^-16; conv error comes only
//  from A's bf16 rounding ~2^-9 rel.)
// ---------------------------------------------------------------------------
__global__ __launch_bounds__(256) void k_prep_w(
    const float* __restrict__ w_dw, unsigned short* __restrict__ wth,
    unsigned short* __restrict__ wtl)
{
    const int k = blockIdx.x;
    const float* W = w_dw + (long)k * 4096;
    unsigned short* th = wth + (long)k * 4096;
    unsigned short* tl = wtl + (long)k * 4096;
    for (int e = threadIdx.x; e < 4096; e += 256) {
        int ci = e >> 6, co = e & 63;
        float v = W[e];
        unsigned short hs = f2bf(v);
        float hf = __uint_as_float((unsigned)hs << 16);
        unsigned short ls = f2bf(v - hf);
        th[co * 64 + ci] = hs;
        tl[co * 64 + ci] = ls;
    }
}

// ---------------------------------------------------------------------------
// K1: sparse conv via MFMA, 2-term split (A bf16, W hi+lo):
//   x@w ~= ah@wh + ah@wl        (error = (x-ah)@w ~ 2^-9 rel, A-rounding only)
// R3/R5 were L3-BW-bound on the A-gather (hi+lo = 32KB/blk-iter ~ 12 B/cyc/CU).
// Halving A bytes (16KB/blk-iter) halves the wall; MFMA count drops 3->2.
// Mechanics identical to the verified R3 kernel: gll staging, XOR swizzle,
// same fragment maps, same epilogue. LDS = Ah 16KB + Bh/Bl 16KB = 32KB.
// ---------------------------------------------------------------------------
__global__ __launch_bounds__(256, 4) void k_conv_mfma(
    const unsigned short* __restrict__ fh,
    const unsigned short* __restrict__ wth, const unsigned short* __restrict__ wtl,
    const float* __restrict__ b_dw, const int* __restrict__ nbr,
    float* __restrict__ xout)
{
    __shared__ unsigned short Ah[128 * 64];
    __shared__ unsigned short Bh[64 * 64];
    __shared__ unsigned short Bl[64 * 64];

    const int t  = threadIdx.x;
    const int wv = t >> 6;          // wave 0..3
    const int l  = t & 63;
    const int v0 = blockIdx.x * 128;
    const int myrow = v0 + wv * 32 + (l & 31);
    const bool rowok = myrow < NN;
    const long nbase = (long)myrow * KKK;

    f32x4 acc[2][4];
#pragma unroll
    for (int i = 0; i < 2; ++i)
#pragma unroll
        for (int j = 0; j < 4; ++j) acc[i][j] = (f32x4){0.f, 0.f, 0.f, 0.f};

    const int lane8 = l >> 3;            // row within 8-row staging group
    const int sl = (l & 7) ^ lane8;      // pre-swizzled source chunk

    int idx = rowok ? nbr[nbase] : NN;

#pragma unroll 1
    for (int k = 0; k < KKK; ++k) {
        __syncthreads();                 // previous compute done reading LDS
        // ---- stage A (bf16 only): wave w covers rows [w*32, w*32+32) ----
#pragma unroll
        for (int i = 0; i < 4; ++i) {
            int rl = i * 8 + lane8;                      // 0..31
            int ridx = __shfl(idx, rl);
            gll16(fh + (long)ridx * 64 + sl * 8, &Ah[(wv * 32 + i * 8) * 64]);
        }
        // ---- stage B (W_k^T hi+lo): wave w covers co rows [w*16, w*16+16) ----
#pragma unroll
        for (int i = 0; i < 2; ++i) {
            int co = wv * 16 + i * 8 + lane8;
            gll16(wth + (long)k * 4096 + co * 64 + sl * 8, &Bh[(wv * 16 + i * 8) * 64]);
            gll16(wtl + (long)k * 4096 + co * 64 + sl * 8, &Bl[(wv * 16 + i * 8) * 64]);
        }
        // ---- prefetch next k's gather index (drained by same vmcnt(0)) ----
        {
            int kn = (k + 1 < KKK) ? k + 1 : KKK - 1;
            idx = rowok ? nbr[nbase + kn] : NN;
        }
        __syncthreads();                 // staging visible
        // ---- compute: 2 ksteps x (2rt x 4ct) x 2 MFMAs ----
#pragma unroll
        for (int ks = 0; ks < 2; ++ks) {
            const int slot = (((l >> 4) + ks * 4) ^ (l & 7)) * 8;
            bf16x8 ahf[2], bhf[4], blf[4];
#pragma unroll
            for (int rt = 0; rt < 2; ++rt) {
                int row = wv * 32 + rt * 16 + (l & 15);
                ahf[rt] = *(const bf16x8*)&Ah[row * 64 + slot];
            }
#pragma unroll
            for (int ct = 0; ct < 4; ++ct) {
                int co = ct * 16 + (l & 15);
                bhf[ct] = *(const bf16x8*)&Bh[co * 64 + slot];
                blf[ct] = *(const bf16x8*)&Bl[co * 64 + slot];
            }
#pragma unroll
            for (int rt = 0; rt < 2; ++rt)
#pragma unroll
                for (int ct = 0; ct < 4; ++ct) {
                    acc[rt][ct] = __builtin_amdgcn_mfma_f32_16x16x32_bf16(
                        ahf[rt], bhf[ct], acc[rt][ct], 0, 0, 0);
                    acc[rt][ct] = __builtin_amdgcn_mfma_f32_16x16x32_bf16(
                        ahf[rt], blf[ct], acc[rt][ct], 0, 0, 0);
                }
        }
    }
    // ---- epilogue: C/D layout col=l&15, row=(l>>4)*4+j ----
#pragma unroll
    for (int ct = 0; ct < 4; ++ct) {
        float bias = b_dw[ct * 16 + (l & 15)];
#pragma unroll
        for (int rt = 0; rt < 2; ++rt)
#pragma unroll
            for (int j = 0; j < 4; ++j) {
                int row = v0 + wv * 32 + rt * 16 + (l >> 4) * 4 + j;
                if (row < NN)
                    xout[(long)row * 64 + ct * 16 + (l & 15)] = acc[rt][ct][j] + bias;
            }
    }
}

// ---------------------------------------------------------------------------
// K2: GroupNorm(1,C) stats per batch: sum, sumsq, count
// stats layout: [s0, s1, q0, q1, cnt0, cnt1]
// ---------------------------------------------------------------------------
__global__ __launch_bounds__(256) void k_gnstats(
    const float* __restrict__ x, const int* __restrict__ batch_ids,
    float* __restrict__ stats)
{
    __shared__ float red[4][8];
    float s0 = 0.f, s1 = 0.f, q0 = 0.f, q1 = 0.f, c0 = 0.f, c1 = 0.f;
    const int total4 = NN * CC / 4;
    for (int i = blockIdx.x * blockDim.x + threadIdx.x; i < total4;
         i += gridDim.x * blockDim.x) {
        float4 v = ((const float4*)x)[i];
        int b = batch_ids[i >> 4];
        float ss = (v.x + v.y) + (v.z + v.w);
        float qq = fmaf(v.x, v.x, fmaf(v.y, v.y, fmaf(v.z, v.z, v.w * v.w)));
        bool b0 = (b == 0);
        s0 += b0 ? ss : 0.f;  s1 += b0 ? 0.f : ss;
        q0 += b0 ? qq : 0.f;  q1 += b0 ? 0.f : qq;
        c0 += b0 ? 4.f : 0.f; c1 += b0 ? 0.f : 4.f;
    }
#pragma unroll
    for (int off = 32; off > 0; off >>= 1) {
        s0 += __shfl_down(s0, off); s1 += __shfl_down(s1, off);
        q0 += __shfl_down(q0, off); q1 += __shfl_down(q1, off);
        c0 += __shfl_down(c0, off); c1 += __shfl_down(c1, off);
    }
    const int lane = threadIdx.x & 63, w = threadIdx.x >> 6;
    if (lane == 0) {
        red[w][0] = s0; red[w][1] = s1; red[w][2] = q0;
        red[w][3] = q1; red[w][4] = c0; red[w][5] = c1;
    }
    __syncthreads();
    if (threadIdx.x < 6) {
        float tot = red[0][threadIdx.x] + red[1][threadIdx.x] +
                    red[2][threadIdx.x] + red[3][threadIdx.x];
        atomicAdd(&stats[threadIdx.x], tot);
    }
}

// ---------------------------------------------------------------------------
// shared helpers for K3/K5
// ---------------------------------------------------------------------------
__device__ __forceinline__ void stage_xn(
    float* __restrict__ sxn, const float* __restrict__ x,
    const int* __restrict__ batch_ids, const float* __restrict__ gn_gamma,
    const float* __restrict__ gn_beta, const float* __restrict__ stats,
    int v0, int t)
{
    float mean[2], rstd[2];
#pragma unroll
    for (int b = 0; b < 2; ++b) {
        float cn  = stats[4 + b];
        float m   = stats[b] / cn;
        float var = stats[2 + b] / cn - m * m;
        mean[b] = m;
        rstd[b] = rsqrtf(var + 1e-6f);
    }
#pragma unroll
    for (int u = 0; u < 4; ++u) {
        int fi = t + u * 256;
        int row = fi >> 4, c4 = fi & 15;
        int vv = v0 + row;
        float4 val = make_float4(0.f, 0.f, 0.f, 0.f);
        if (vv < NN) {
            float4 xv = *(const float4*)(x + ((long)vv << 6) + (c4 << 2));
            float4 g  = *(const float4*)(gn_gamma + (c4 << 2));
            float4 be = *(const float4*)(gn_beta + (c4 << 2));
            int b = batch_ids[vv];
            float m = mean[b], rs = rstd[b];
            val.x = (xv.x - m) * rs * g.x + be.x;
            val.y = (xv.y - m) * rs * g.y + be.y;
            val.z = (xv.z - m) * rs * g.z + be.z;
            val.w = (xv.w - m) * rs * g.w + be.w;
        }
        *(float4*)&sxn[row * 68 + (c4 << 2)] = val;
    }
}

__device__ __forceinline__ void gemm_h(
    const float* __restrict__ sxn, const float* __restrict__ w_pw1,
    int r, int c, float h[4][16])
{
#pragma unroll 2
    for (int ci = 0; ci < 64; ++ci) {
        float a[4];
#pragma unroll
        for (int i = 0; i < 4; ++i) a[i] = sxn[((r << 2) + i) * 68 + ci];
        const float4* wr = (const float4*)(w_pw1 + ci * 256 + (c << 4));
        float4 w4[4] = {wr[0], wr[1], wr[2], wr[3]};
#pragma unroll
        for (int i = 0; i < 4; ++i)
#pragma unroll
            for (int q = 0; q < 4; ++q) {
                h[i][q * 4 + 0] = fmaf(a[i], w4[q].x, h[i][q * 4 + 0]);
                h[i][q * 4 + 1] = fmaf(a[i], w4[q].y, h[i][q * 4 + 1]);
                h[i][q * 4 + 2] = fmaf(a[i], w4[q].z, h[i][q * 4 + 2]);
                h[i][q * 4 + 3] = fmaf(a[i], w4[q].w, h[i][q * 4 + 3]);
            }
    }
}

// ---------------------------------------------------------------------------
// K3: h = relu(GN(x) @ w_pw1); gx2[b][c'] += sum_v h^2
// ---------------------------------------------------------------------------
__global__ __launch_bounds__(256) void k_pw1_grn(
    const float* __restrict__ x, const int* __restrict__ batch_ids,
    const float* __restrict__ gn_gamma, const float* __restrict__ gn_beta,
    const float* __restrict__ w_pw1, const float* __restrict__ stats,
    float* __restrict__ gx2)
{
    __shared__ float sxn[64 * 68];
    __shared__ float red[16 * 257];
    const int t = threadIdx.x;
    const int v0 = blockIdx.x * 64;
    stage_xn(sxn, x, batch_ids, gn_gamma, gn_beta, stats, v0, t);
    __syncthreads();
    const int r = t >> 4, c = t & 15;
    float h[4][16] = {};
    gemm_h(sxn, w_pw1, r, c, h);
#pragma unroll
    for (int i = 0; i < 4; ++i)
#pragma unroll
        for (int jj = 0; jj < 16; ++jj) h[i][jj] = fmaxf(h[i][jj], 0.f);

    int bv[4];
#pragma unroll
    for (int i = 0; i < 4; ++i) {
        int vv = v0 + (r << 2) + i;
        bv[i] = (vv < NN) ? batch_ids[vv] : -1;
    }
#pragma unroll
    for (int b = 0; b < 2; ++b) {
        float p[16] = {};
#pragma unroll
        for (int i = 0; i < 4; ++i)
            if (bv[i] == b)
#pragma unroll
                for (int jj = 0; jj < 16; ++jj)
                    p[jj] = fmaf(h[i][jj], h[i][jj], p[jj]);
#pragma unroll
        for (int jj = 0; jj < 16; ++jj)
            red[r * 257 + (c << 4) + jj] = p[jj];
        __syncthreads();
        float sum = 0.f;
#pragma unroll
        for (int rr = 0; rr < 16; ++rr) sum += red[rr * 257 + t];
        if (sum != 0.f) atomicAdd(&gx2[b * 256 + t], sum);
        __syncthreads();
    }
}

// ---------------------------------------------------------------------------
// K4: nx[b][c'] = gx / (mean_c'(gx) + eps), gx = sqrt(gx2). One block.
// ---------------------------------------------------------------------------
__global__ __launch_bounds__(256) void k_grn_nx(
    const float* __restrict__ gx2, float* __restrict__ nx)
{
    __shared__ float red[8];
    const int t = threadIdx.x;
#pragma unroll
    for (int b = 0; b < 2; ++b) {
        float g = sqrtf(gx2[b * 256 + t]);
        float s = g;
#pragma unroll
        for (int off = 32; off > 0; off >>= 1) s += __shfl_down(s, off);
        if ((t & 63) == 0) red[t >> 6] = s;
        __syncthreads();
        float meang = (red[0] + red[1] + red[2] + red[3]) * (1.f / 256.f);
        nx[b * 256 + t] = g / (meang + 1e-6f);
        __syncthreads();
    }
}

// ---------------------------------------------------------------------------
// K5: recompute xn and h, apply GRN, y @ w_pw2, + identity -> out
// ---------------------------------------------------------------------------
__global__ __launch_bounds__(256) void k_pw2_out(
    const float* __restrict__ x, const float* __restrict__ feats,
    const int* __restrict__ batch_ids, const float* __restrict__ gn_gamma,
    const float* __restrict__ gn_beta, const float* __restrict__ w_pw1,
    const float* __restrict__ grn_gamma, const float* __restrict__ grn_beta,
    const float* __restrict__ w_pw2, const float* __restrict__ stats,
    const float* __restrict__ nx, float* __restrict__ out)
{
    __shared__ float smem[64 * 132];
    const int t = threadIdx.x;
    const int v0 = blockIdx.x * 64;
    stage_xn(smem, x, batch_ids, gn_gamma, gn_beta, stats, v0, t);
    __syncthreads();
    const int r = t >> 4, c = t & 15;
    float h[4][16] = {};
    gemm_h(smem, w_pw1, r, c, h);

    int bv[4];
#pragma unroll
    for (int i = 0; i < 4; ++i) {
        int vv = v0 + (r << 2) + i;
        bv[i] = (vv < NN) ? batch_ids[vv] : 0;
    }
#pragma unroll
    for (int q = 0; q < 4; ++q) {
        const int ch = (c << 4) + (q << 2);
        float4 ga  = *(const float4*)(grn_gamma + ch);
        float4 gbv = *(const float4*)(grn_beta + ch);
        float4 n0  = *(const float4*)(nx + ch);
        float4 n1  = *(const float4*)(nx + 256 + ch);
#pragma unroll
        for (int i = 0; i < 4; ++i) {
            float4 ns = bv[i] ? n1 : n0;
            float h0 = fmaxf(h[i][q * 4 + 0], 0.f);
            float h1 = fmaxf(h[i][q * 4 + 1], 0.f);
            float h2 = fmaxf(h[i][q * 4 + 2], 0.f);
            float h3 = fmaxf(h[i][q * 4 + 3], 0.f);
            h[i][q * 4 + 0] = fmaf(ga.x, h0 * ns.x, gbv.x) + h0;
            h[i][q * 4 + 1] = fmaf(ga.y, h1 * ns.y, gbv.y) + h1;
            h[i][q * 4 + 2] = fmaf(ga.z, h2 * ns.z, gbv.z) + h2;
            h[i][q * 4 + 3] = fmaf(ga.w, h3 * ns.w, gbv.w) + h3;
        }
    }

    float acc2[4][4] = {};
#pragma unroll
    for (int half = 0; half < 2; ++half) {
        __syncthreads();
        if ((c >> 3) == half) {
            const int ch0 = (c & 7) << 4;
#pragma unroll
            for (int i = 0; i < 4; ++i) {
                float4* dst = (float4*)&smem[((r << 2) + i) * 132 + ch0];
                dst[0] = make_float4(h[i][0],  h[i][1],  h[i][2],  h[i][3]);
                dst[1] = make_float4(h[i][4],  h[i][5],  h[i][6],  h[i][7]);
                dst[2] = make_float4(h[i][8],  h[i][9],  h[i][10], h[i][11]);
                dst[3] = make_float4(h[i][12], h[i][13], h[i][14], h[i][15]);
            }
        }
        __syncthreads();
#pragma unroll 4
        for (int kk = 0; kk < 128; ++kk) {
            float a0 = smem[((r << 2) + 0) * 132 + kk];
            float a1 = smem[((r << 2) + 1) * 132 + kk];
            float a2 = smem[((r << 2) + 2) * 132 + kk];
            float a3 = smem[((r << 2) + 3) * 132 + kk];
            float4 w = *(const float4*)(w_pw2 + (half * 128 + kk) * 64 + (c << 2));
            acc2[0][0] = fmaf(a0, w.x, acc2[0][0]); acc2[0][1] = fmaf(a0, w.y, acc2[0][1]);
            acc2[0][2] = fmaf(a0, w.z, acc2[0][2]); acc2[0][3] = fmaf(a0, w.w, acc2[0][3]);
            acc2[1][0] = fmaf(a1, w.x, acc2[1][0]); acc2[1][1] = fmaf(a1, w.y, acc2[1][1]);
            acc2[1][2] = fmaf(a1, w.z, acc2[1][2]); acc2[1][3] = fmaf(a1, w.w, acc2[1][3]);
            acc2[2][0] = fmaf(a2, w.x, acc2[2][0]); acc2[2][1] = fmaf(a2, w.y, acc2[2][1]);
            acc2[2][2] = fmaf(a2, w.z, acc2[2][2]); acc2[2][3] = fmaf(a2, w.w, acc2[2][3]);
            acc2[3][0] = fmaf(a3, w.x, acc2[3][0]); acc2[3][1] = fmaf(a3, w.y, acc2[3][1]);
            acc2[3][2] = fmaf(a3, w.z, acc2[3][2]); acc2[3][3] = fmaf(a3, w.w, acc2[3][3]);
        }
    }
#pragma unroll
    for (int i = 0; i < 4; ++i) {
        int vv = v0 + (r << 2) + i;
        if (vv < NN) {
            float4 fin = *(const float4*)(feats + ((long)vv << 6) + (c << 2));
            float4 o = make_float4(fin.x + acc2[i][0], fin.y + acc2[i][1],
                                   fin.z + acc2[i][2], fin.w + acc2[i][3]);
            *(float4*)(out + ((long)vv << 6) + (c << 2)) = o;
        }
    }
}

// ---------------------------------------------------------------------------
extern "C" void kernel_launch(void* const* d_in, const int* in_sizes, int n_in,
                              void* d_out, int out_size, void* d_ws, size_t ws_size,
                              hipStream_t stream)
{
    const float* feats     = (const float*)d_in[0];
    const float* w_dw      = (const float*)d_in[1];
    const float* b_dw      = (const float*)d_in[2];
    const float* gn_gamma  = (const float*)d_in[3];
    const float* gn_beta   = (const float*)d_in[4];
    const float* w_pw1     = (const float*)d_in[5];
    const float* grn_gamma = (const float*)d_in[6];
    const float* grn_beta  = (const float*)d_in[7];
    const float* w_pw2     = (const float*)d_in[8];
    const int*   nbr       = (const int*)d_in[9];
    const int*   batch_ids = (const int*)d_in[10];
    float* out = (float*)d_out;

    char* ws = (char*)d_ws;
    float*          x     = (float*)ws;                    ws += (size_t)NN * CC * 4;
    unsigned short* fh    = (unsigned short*)ws;           ws += (size_t)(NN + 1) * CC * 2;
    unsigned short* wth   = (unsigned short*)ws;           ws += (size_t)KKK * 4096 * 2;
    unsigned short* wtl   = (unsigned short*)ws;           ws += (size_t)KKK * 4096 * 2;
    float*          stats = (float*)ws;                    ws += 8 * 4;
    float*          gx2   = (float*)ws;                    ws += 512 * 4;
    float*          nx    = (float*)ws;

    hipMemsetAsync(stats, 0, (8 + 512 + 512) * sizeof(float), stream);

    const int pf_blocks = ((NN + 1) * CC / 4 + 255) / 256;
    k_prep_feats<<<pf_blocks, 256, 0, stream>>>(feats, fh);
    k_prep_w<<<KKK, 256, 0, stream>>>(w_dw, wth, wtl);

    const int cblk = (NN + 127) / 128;          // 782
    k_conv_mfma<<<cblk, 256, 0, stream>>>(fh, wth, wtl, b_dw, nbr, x);

    const int nblk = (NN + 63) / 64;            // 1563
    k_gnstats<<<1024, 256, 0, stream>>>(x, batch_ids, stats);
    k_pw1_grn<<<nblk, 256, 0, stream>>>(x, batch_ids, gn_gamma, gn_beta,
                                        w_pw1, stats, gx2);
    k_grn_nx<<<1, 256, 0, stream>>>(gx2, nx);
    k_pw2_out<<<nblk, 256, 0, stream>>>(x, feats, batch_ids, gn_gamma, gn_beta,
                                        w_pw1, grn_gamma, grn_beta, w_pw2,
                                        stats, nx, out);
}